// Round 7
// baseline (886.470 us; speedup 1.0000x reference)
//
#include <hip/hip_runtime.h>
#include <hip/hip_bf16.h>

// ============================================================================
// RecurrentDecoder v16: 162-block persistent kernel, flag dataflow.
// v15 post-mortem: mel-fold REGRESSED (+0.8us/step: waves 6-7's 48-deep
// dependent MFMA chain + store drain at stage_c4's vmcnt(0) didn't hide
// under the ctxdone wait; hdone join spread it to all blocks). Withdrawn.
// v16 = v13 (best measured, 737us steady) + two latency-overlap edits that
// change ONLY lane assignment / publish scheduling, not the protocol:
//  1. Polls moved to idle waves, overlapped with compute/publish:
//     - GRU ctxdone wait (128 flags) -> waves 6-7, concurrent with waves
//       0-5's part-1 MFMAs (was serial after part 1 on waves 0-1).
//     - att hdone wait -> wave 2, concurrent with wave 0's (previous-step)
//       fused publish. GRU hdone wait -> wave 6, same overlap.
//  2. Fused single-wave publish+flag (both sides): wave 0 reads packed
//     result from LDS, one wide coherent store per lane, vmcnt(0) inside
//     the asm, lane 0 posts flag immediately. Deletes one barrier + the
//     cross-wave flag handoff per step per side; loop-top sync is the join.
//     GRU h-slice: 256 dwords = 64 lanes x dwordx4 @ (l>>1)*256+dt*8+(l&1)*4.
//     att ctx: 128 dwords = 64 lanes x dwordx2, cp-combine folded in.
// Everything else byte-identical to v13: 4-way e-split att (128 blocks),
// block-local softmax, shfl 8/16/32 reductions, partial-ctx quarters,
// GRU K=1024 with WC[kt&7], stage_c4 single round-trip, mel blocks 160-161,
// meldone backpressure, s_sleep waitge.
// ============================================================================

#define LOG2E 1.4426950408889634f
#define FLAGS_MAGIC 0x13572468u
#define SMEM_BYTES 138752
#define NBLK 162

typedef __attribute__((ext_vector_type(8))) short bf8;
typedef __attribute__((ext_vector_type(4))) float f32x4;
typedef __attribute__((ext_vector_type(4))) unsigned u32x4;
typedef unsigned long long ull;

#define EX2(x) exp2f(x)
#define MFMA16(a, b, c) __builtin_amdgcn_mfma_f32_16x16x32_bf16(a, b, c, 0, 0, 0)

struct Params {
  const float* dec;
  const float* ali;
  const float* watt;
  const float* wih;
  const float* whh;
  const float* wmel;
  const float* bmel;
  const float* wgate;
  const float* bgate;
  float* out;
  unsigned* bar;  // [0]=magic [16]=p0cnt [32+16i]=hdone(32) [544+16j]=ctxdone(128)
                  // [2592+16m]=meldone(2)
  __hip_bfloat16* wihb;    // [1536][512]
  __hip_bfloat16* whhb;    // [1536][512]
  __hip_bfloat16* wmelgb;  // [96][768]
  __hip_bfloat16* seqb;    // [64][32][256]
  __hip_bfloat16* hbf;     // ring [4][32][512]
  __hip_bfloat16* ctxb;    // ring [4][128][256]  (hb = q4*32+b, partial quarters)
  unsigned* wattp;         // [256][256] packed bf16 pairs of W_att^T
};

__device__ __forceinline__ bf8 ldfrag(const __hip_bfloat16* p) { return *(const bf8*)p; }
__device__ __forceinline__ float sigm(float x) { return 1.0f / (1.0f + EX2(-x * LOG2E)); }
__device__ __forceinline__ float tanhfast(float x) {
  x = fminf(fmaxf(x, -15.0f), 15.0f);
  float e = EX2(x * (2.0f * LOG2E));
  return (e - 1.0f) / (e + 1.0f);
}
__device__ __forceinline__ float btof(unsigned v) { return __uint_as_float(v << 16); }
__device__ __forceinline__ unsigned short f2bfbits(float x) {
  __hip_bfloat16 h = __float2bfloat16(x);
  return *(unsigned short*)&h;
}
__device__ __forceinline__ unsigned sysld32(const unsigned* p) {
  return __hip_atomic_load(p, __ATOMIC_RELAXED, __HIP_MEMORY_SCOPE_SYSTEM);
}
__device__ __forceinline__ ull sysld64(const ull* p) {
  return __hip_atomic_load(p, __ATOMIC_RELAXED, __HIP_MEMORY_SCOPE_SYSTEM);
}
__device__ __forceinline__ void sysst32(unsigned* p, unsigned v) {
  __hip_atomic_store(p, v, __ATOMIC_RELAXED, __HIP_MEMORY_SCOPE_SYSTEM);
}
__device__ __forceinline__ void sysst64(ull* p, ull v) {
  __hip_atomic_store(p, v, __ATOMIC_RELAXED, __HIP_MEMORY_SCOPE_SYSTEM);
}
// Coherent store + drain inside one asm block (store-ack before flag post).
__device__ __forceinline__ void sysst8_drain(void* dst, ull v) {
  asm volatile("global_store_dwordx2 %0, %1, off sc0 sc1\n\ts_waitcnt vmcnt(0)"
               :: "v"(dst), "v"(v) : "memory");
}
__device__ __forceinline__ void sysst16_drain(void* dst, u32x4 v) {
  asm volatile("global_store_dwordx4 %0, %1, off sc0 sc1\n\ts_waitcnt vmcnt(0)"
               :: "v"(dst), "v"(v) : "memory");
}
__device__ __forceinline__ void sysld16x4(u32x4* d0, u32x4* d1, u32x4* d2, u32x4* d3,
                                          const void* p0, const void* p1,
                                          const void* p2, const void* p3) {
  u32x4 a, b, c, d;
  asm volatile(
      "global_load_dwordx4 %0, %4, off sc0 sc1\n\t"
      "global_load_dwordx4 %1, %5, off sc0 sc1\n\t"
      "global_load_dwordx4 %2, %6, off sc0 sc1\n\t"
      "global_load_dwordx4 %3, %7, off sc0 sc1\n\t"
      "s_waitcnt vmcnt(0)"
      : "=&v"(a), "=&v"(b), "=&v"(c), "=&v"(d)
      : "v"(p0), "v"(p1), "v"(p2), "v"(p3)
      : "memory");
  *d0 = a; *d1 = b; *d2 = c; *d3 = d;
}
// 8 coherent dwordx4 loads, ONE vmcnt(0): single round-trip staging.
__device__ __forceinline__ void sysld16x8(u32x4* d0, u32x4* d1, u32x4* d2, u32x4* d3,
                                          u32x4* d4, u32x4* d5, u32x4* d6, u32x4* d7,
                                          const void* p0, const void* p1,
                                          const void* p2, const void* p3,
                                          const void* p4, const void* p5,
                                          const void* p6, const void* p7) {
  u32x4 a, b, c, d, e, f, g, h;
  asm volatile(
      "global_load_dwordx4 %0, %8, off sc0 sc1\n\t"
      "global_load_dwordx4 %1, %9, off sc0 sc1\n\t"
      "global_load_dwordx4 %2, %10, off sc0 sc1\n\t"
      "global_load_dwordx4 %3, %11, off sc0 sc1\n\t"
      "global_load_dwordx4 %4, %12, off sc0 sc1\n\t"
      "global_load_dwordx4 %5, %13, off sc0 sc1\n\t"
      "global_load_dwordx4 %6, %14, off sc0 sc1\n\t"
      "global_load_dwordx4 %7, %15, off sc0 sc1\n\t"
      "s_waitcnt vmcnt(0)"
      : "=&v"(a), "=&v"(b), "=&v"(c), "=&v"(d),
        "=&v"(e), "=&v"(f), "=&v"(g), "=&v"(h)
      : "v"(p0), "v"(p1), "v"(p2), "v"(p3),
        "v"(p4), "v"(p5), "v"(p6), "v"(p7)
      : "memory");
  *d0 = a; *d1 = b; *d2 = c; *d3 = d;
  *d4 = e; *d5 = f; *d6 = g; *d7 = h;
}
__device__ __forceinline__ void waitge(unsigned* w, unsigned tgt) {
  while (sysld32(w) < tgt) __builtin_amdgcn_s_sleep(1);
}

__device__ __forceinline__ void p0bar(unsigned* bar) {
  __syncthreads();
  if (threadIdx.x == 0) {
    __builtin_amdgcn_fence(__ATOMIC_RELEASE, "agent");
    __hip_atomic_fetch_add(bar + 16, 1u, __ATOMIC_RELAXED, __HIP_MEMORY_SCOPE_SYSTEM);
    while (sysld32(bar + 16) < (unsigned)NBLK) __builtin_amdgcn_s_sleep(1);
    __builtin_amdgcn_fence(__ATOMIC_ACQUIRE, "agent");
  }
  __syncthreads();
}

// P0 conversion work for blocks 128..161 (wid in [0, 34*512))
__device__ __forceinline__ void p0a_worker(const Params& p, int wid) {
  for (int i = wid; i < 2252800; i += 17408) {
    if (i < 786432) {
      p.wihb[i] = __float2bfloat16(p.wih[i]);
    } else if (i < 1572864) {
      int j = i - 786432;
      p.whhb[j] = __float2bfloat16(p.whh[j]);
    } else if (i < 2097152) {
      int j = i - 1572864;
      int s = j >> 13;
      p.seqb[j] = (s == 0) ? __float2bfloat16(0.0f) : __float2bfloat16(p.dec[j - 8192]);
    } else if (i < 2170880) {
      int j = i - 2097152;
      int r = j / 768, c = j - r * 768;
      float v = (r < 80) ? p.wmel[j] : ((r == 80) ? p.wgate[c] : 0.0f);
      p.wmelgb[j] = __float2bfloat16(v);
    } else if (i < 2236416) {
      int j = i - 2170880;
      int kp = j >> 8, e = j & 255;
      unsigned lo = f2bfbits(p.watt[e * 512 + 2 * kp]);
      unsigned hi = f2bfbits(p.watt[e * 512 + 2 * kp + 1]);
      p.wattp[j] = lo | (hi << 16);
    } else {
      int j = i - 2236416;
      p.hbf[j] = __float2bfloat16(0.0f);  // h ring slot 0 = h(0) = 0
    }
  }
}

// Stage h[32][512] (row-major, coherent) into fragment-major LDS (32 sections).
__device__ __forceinline__ void stage_h_frag(__hip_bfloat16* hA,
                                             const __hip_bfloat16* hsrc, int tid) {
  const int lm = tid & 15, lq = (tid >> 4) & 3, wq = tid >> 6;
  const int dst_in = (lq * 16 + lm) * 8;
  const int i0 = wq, i1 = 8 + wq, i2 = 16 + wq, i3 = 24 + wq;
  auto soff = [&](int idx) {
    return ((idx >> 4) * 16 + lm) * 512 + (idx & 15) * 32 + lq * 8;
  };
  u32x4 a, b, c, d;
  sysld16x4(&a, &b, &c, &d, hsrc + soff(i0), hsrc + soff(i1), hsrc + soff(i2),
            hsrc + soff(i3));
  u32x4* dst = (u32x4*)hA;
  dst[(i0 * 512 + dst_in) >> 3] = a;
  dst[(i1 * 512 + dst_in) >> 3] = b;
  dst[(i2 * 512 + dst_in) >> 3] = c;
  dst[(i3 * 512 + dst_in) >> 3] = d;
}
// Stage concat-ctx [b, k=q4*256+e] (src ctxb slot: [128][256], hb=q4*32+b) into
// fragment-major LDS (64 sections over K=1024). Single coherent round-trip.
__device__ __forceinline__ void stage_c4(__hip_bfloat16* cA,
                                         const __hip_bfloat16* csrc, int tid) {
  const int lm = tid & 15, lq = (tid >> 4) & 3, wq = tid >> 6;
  const int dst_in = (lq * 16 + lm) * 8;
  u32x4* dst = (u32x4*)cA;
  auto soff = [&](int idx) {
    int mt = idx >> 5, kt = idx & 31;
    int bb = mt * 16 + lm;
    int k = kt * 32 + lq * 8;
    return ((k >> 8) * 32 + bb) * 256 + (k & 255);
  };
  const int i0 = wq, i1 = 8 + wq, i2 = 16 + wq, i3 = 24 + wq;
  const int i4 = 32 + wq, i5 = 40 + wq, i6 = 48 + wq, i7 = 56 + wq;
  u32x4 a, b, c, d, e, f, g, h;
  sysld16x8(&a, &b, &c, &d, &e, &f, &g, &h,
            csrc + soff(i0), csrc + soff(i1), csrc + soff(i2), csrc + soff(i3),
            csrc + soff(i4), csrc + soff(i5), csrc + soff(i6), csrc + soff(i7));
  dst[(i0 * 512 + dst_in) >> 3] = a;
  dst[(i1 * 512 + dst_in) >> 3] = b;
  dst[(i2 * 512 + dst_in) >> 3] = c;
  dst[(i3 * 512 + dst_in) >> 3] = d;
  dst[(i4 * 512 + dst_in) >> 3] = e;
  dst[(i5 * 512 + dst_in) >> 3] = f;
  dst[(i6 * 512 + dst_in) >> 3] = g;
  dst[(i7 * 512 + dst_in) >> 3] = h;
}

__global__ void __launch_bounds__(512, 1) rdec_kernel(Params p) {
  const int tid = threadIdx.x;
  const int bid = blockIdx.x;
  extern __shared__ char smem[];
  unsigned* hdone = p.bar + 32;      // 32 flags
  unsigned* ctxdone = p.bar + 544;   // 128 flags
  unsigned* meldone = p.bar + 2592;  // 2 flags

  if (bid == 0) {
    for (int i = 1 + tid; i < 2624; i += 512) sysst32(p.bar + i, 0u);
    __syncthreads();
    if (tid == 0) sysst32(p.bar, FLAGS_MAGIC);
  }

  if (bid < 128) {
    // =================== ATT path (batch b, e-quarter q4) ===================
    const int b = bid >> 2, q4 = bid & 3, hb = q4 * 32 + b;
    unsigned short* alds = (unsigned short*)smem;  // [256 f][260 t] bf16 (pad)
    float* fb = (float*)(smem + 133120);
    float* shh = fb;          // 512   h(s)[b,:]
    float* p2l = fb + 512;    // 64    proj_e * LOG2E (my e-quarter)
    float* rzl = fb + 576;    // 64    1/Z_e
    float* tw = fb + 640;     // 256   tw (my e-quarter contribution)
    float* cp = fb + 896;     // [2][256] ctx partial reduce

    // el in lane LOW bits (bank spread), kq in lane bits 3..5 (shfl 8/16/32)
    const int el = (tid & 7) | ((tid >> 6) << 3);  // e-local / t-quad (0..63)
    const int kq = (tid >> 3) & 7;                 // k-/t-eighth / e-group
    const int f = tid & 255, th = tid >> 8;        // ctx mapping

    // P0: full a[:,b,:] -> alds[f][t]
    for (int i = tid; i < 65536; i += 512) {
      int t = i >> 8, ee = i & 255;
      alds[ee * 260 + t] = f2bfbits(p.ali[t * 8192 + b * 256 + ee]);
    }
    if (tid == 0) {
      while (sysld32(p.bar) != FLAGS_MAGIC) __builtin_amdgcn_s_sleep(1);
    }
    p0bar(p.bar);
    // k-strided weight regs: kp = i*8 + kq
    unsigned wr[32];
#pragma unroll
    for (int i = 0; i < 32; ++i) wr[i] = p.wattp[(i * 8 + kq) * 256 + q4 * 64 + el];

    for (int s = 0; s < 64; ++s) {
      // polls on wave 2 lanes (overlap with wave 0's previous-step publish)
      if (tid >= 128 && tid < 160) waitge(hdone + (tid - 128) * 16, (unsigned)s);
      else if (tid >= 160 && tid < 162)
        waitge(meldone + (tid - 160) * 16, (s >= 4) ? (unsigned)(s - 3) : 0u);
      __syncthreads();
      // h(s)[b,:] -> shh fp32
      if (tid < 128) {
        ull w = sysld64((const ull*)(p.hbf + (s & 3) * 16384 + b * 512) + tid);
        shh[tid * 4 + 0] = btof((unsigned)(w & 0xffff));
        shh[tid * 4 + 1] = btof((unsigned)((w >> 16) & 0xffff));
        shh[tid * 4 + 2] = btof((unsigned)((w >> 32) & 0xffff));
        shh[tid * 4 + 3] = btof((unsigned)((w >> 48) & 0xffff));
      }
      __syncthreads();
      // proj (k-eighth) + Z (t-eighth) fused in-register, shfl 8/16/32
      {
        const float2* h2 = (const float2*)shh;
        float a0 = 0.f, a1 = 0.f;
#pragma unroll
        for (int i = 0; i < 32; i += 2) {
          unsigned w0 = wr[i], w1 = wr[i + 1];
          float2 h0 = h2[i * 8 + kq], h1 = h2[(i + 1) * 8 + kq];
          a0 = fmaf(__uint_as_float(w0 << 16), h0.x, a0);
          a0 = fmaf(__uint_as_float(w0 & 0xffff0000u), h0.y, a0);
          a1 = fmaf(__uint_as_float(w1 << 16), h1.x, a1);
          a1 = fmaf(__uint_as_float(w1 & 0xffff0000u), h1.y, a1);
        }
        float pr = a0 + a1;
        pr += __shfl_xor(pr, 8);
        pr += __shfl_xor(pr, 16);
        pr += __shfl_xor(pr, 32);
        const float pp = pr * LOG2E;
        // Z partial over my t-eighth (32 t)
        const unsigned short* ap = alds + (q4 * 64 + el) * 260 + kq * 32;
        float z0 = 0.f, z1 = 0.f;
#pragma unroll
        for (int j = 0; j < 8; ++j) {
          ushort4 v = *(const ushort4*)(ap + j * 4);
          z0 += EX2(btof(v.x) * pp) + EX2(btof(v.y) * pp);
          z1 += EX2(btof(v.z) * pp) + EX2(btof(v.w) * pp);
        }
        float zz = z0 + z1;
        zz += __shfl_xor(zz, 8);
        zz += __shfl_xor(zz, 16);
        zz += __shfl_xor(zz, 32);
        if (kq == 0) {
          p2l[el] = pp;
          rzl[el] = 1.0f / zz;
        }
      }
      __syncthreads();
      // pass2: tw_t = sum_e u/Z over my 64 e; shfl 8/16/32 over e-groups
      {
        float t0 = 0.f, t1 = 0.f, t2 = 0.f, t3 = 0.f;
#pragma unroll
        for (int j = 0; j < 8; ++j) {
          const int e2 = kq * 8 + j;
          ushort4 v = *(const ushort4*)(alds + (q4 * 64 + e2) * 260 + el * 4);
          const float ppj = p2l[e2], rr = rzl[e2];
          t0 = fmaf(EX2(btof(v.x) * ppj), rr, t0);
          t1 = fmaf(EX2(btof(v.y) * ppj), rr, t1);
          t2 = fmaf(EX2(btof(v.z) * ppj), rr, t2);
          t3 = fmaf(EX2(btof(v.w) * ppj), rr, t3);
        }
        t0 += __shfl_xor(t0, 8); t0 += __shfl_xor(t0, 16); t0 += __shfl_xor(t0, 32);
        t1 += __shfl_xor(t1, 8); t1 += __shfl_xor(t1, 16); t1 += __shfl_xor(t1, 32);
        t2 += __shfl_xor(t2, 8); t2 += __shfl_xor(t2, 16); t2 += __shfl_xor(t2, 32);
        t3 += __shfl_xor(t3, 8); t3 += __shfl_xor(t3, 16); t3 += __shfl_xor(t3, 32);
        if (kq == 0) *(float4*)(tw + el * 4) = make_float4(t0, t1, t2, t3);
      }
      __syncthreads();
      // ctx partial: ALL 256 f, t-half per th (sum of 4 quarters lands in GRU MFMA)
      {
        const unsigned short* ap = alds + f * 260 + th * 128;
        const float4* twv = (const float4*)(tw + th * 128);
        float c0 = 0.f, c1 = 0.f;
#pragma unroll 4
        for (int j = 0; j < 32; ++j) {
          ushort4 v = *(const ushort4*)(ap + j * 4);
          float4 t4 = twv[j];
          c0 += t4.x * btof(v.x) + t4.y * btof(v.y);
          c1 += t4.z * btof(v.z) + t4.w * btof(v.w);
        }
        cp[th * 256 + f] = c0 + c1;
      }
      __syncthreads();
      // fused single-wave publish: wave 0 combines halves, packs bf16 pairs,
      // one dwordx2 coherent store/lane, drain, lane 0 posts flag. No sync.
      if (tid < 64) {
        float4 ca = *(const float4*)(cp + 4 * tid);
        float4 cb = *(const float4*)(cp + 256 + 4 * tid);
        unsigned u0 = (unsigned)f2bfbits(ca.x + cb.x) |
                      ((unsigned)f2bfbits(ca.y + cb.y) << 16);
        unsigned u1 = (unsigned)f2bfbits(ca.z + cb.z) |
                      ((unsigned)f2bfbits(ca.w + cb.w) << 16);
        unsigned* dst = (unsigned*)(p.ctxb + ((s & 3) * 128 + hb) * 256) + 2 * tid;
        sysst8_drain(dst, (ull)u0 | ((ull)u1 << 32));
        if (tid == 0) sysst32(ctxdone + hb * 16, (unsigned)(s + 1));
      }
      // loop-top __syncthreads is the join
    }
  } else if (bid < 160) {
    // ============================ GRU path ============================
    const int dt = bid - 128;
    const int wv = tid >> 6;
    const bool act = wv < 6;
    const int l = tid & 63, lm = l & 15, lq = l >> 4;
    const int g = wv % 3, mt = wv / 3;
    const int am = mt * 16 + lm;
    const int brow = g * 512 + dt * 16 + lm;
    __hip_bfloat16* hA = (__hip_bfloat16*)smem;             // frag-major 32KB
    __hip_bfloat16* cA = (__hip_bfloat16*)(smem + 32768);   // frag-major 64KB (K=1024)
    float* pw = (float*)(smem + 98304);                     // [8][16][17]
    unsigned short* h16 = (unsigned short*)(smem + 107008); // [512]
    p0a_worker(p, (bid - 128) * 512 + tid);
    if (tid == 0) {
      while (sysld32(p.bar) != FLAGS_MAGIC) __builtin_amdgcn_s_sleep(1);
    }
    p0bar(p.bar);
    bf8 WH[16], WD[8], WC[8];
    if (act) {
#pragma unroll
      for (int kt = 0; kt < 16; ++kt) WH[kt] = ldfrag(p.whhb + brow * 512 + kt * 32 + lq * 8);
#pragma unroll
      for (int kt = 0; kt < 8; ++kt) WD[kt] = ldfrag(p.wihb + brow * 512 + kt * 32 + lq * 8);
#pragma unroll
      for (int kt = 0; kt < 8; ++kt) WC[kt] = ldfrag(p.wihb + brow * 512 + 256 + kt * 32 + lq * 8);
    }
    for (int s = 0; s < 64; ++s) {
      // polls on wave 6 lanes (overlap with wave 0's previous-step publish)
      if (tid >= 384 && tid < 416) waitge(hdone + (tid - 384) * 16, (unsigned)s);
      else if (tid >= 416 && tid < 418)
        waitge(meldone + (tid - 416) * 16, (s >= 4) ? (unsigned)(s - 3) : 0u);
      __syncthreads();
      stage_h_frag(hA, p.hbf + (s & 3) * 16384, tid);
      __syncthreads();
      f32x4 acc = {0.f, 0.f, 0.f, 0.f};
      f32x4 gi = {0.f, 0.f, 0.f, 0.f};
      if (act) {
#pragma unroll
        for (int kt = 0; kt < 16; ++kt) {
          bf8 a = ldfrag(hA + (mt * 16 + kt) * 512 + l * 8);
          acc = MFMA16(a, WH[kt], acc);
        }
        const __hip_bfloat16* seqp = p.seqb + s * 8192;
#pragma unroll
        for (int kt = 0; kt < 8; ++kt) {
          bf8 a = ldfrag(seqp + am * 256 + kt * 32 + lq * 8);
          gi = MFMA16(a, WD[kt], gi);
        }
      }
      // ctxdone poll on waves 6-7 (128 lanes), CONCURRENT with part-1 MFMAs
      if (tid >= 384) waitge(ctxdone + (tid - 384) * 16, (unsigned)(s + 1));
      __syncthreads();
      stage_c4(cA, p.ctxb + (s & 3) * 32768, tid);
      __syncthreads();
      if (act) {
        // gi_ctx over K=1024 concat quarters with duplicated W rows
#pragma unroll
        for (int kt = 0; kt < 32; ++kt) {
          bf8 a = ldfrag(cA + (mt * 32 + kt) * 512 + l * 8);
          gi = MFMA16(a, WC[kt & 7], gi);
        }
        if (g < 2) {
#pragma unroll
          for (int r = 0; r < 4; ++r) pw[(wv * 16 + lq * 4 + r) * 17 + lm] = acc[r] + gi[r];
        } else {
#pragma unroll
          for (int r = 0; r < 4; ++r) pw[(wv * 16 + lq * 4 + r) * 17 + lm] = acc[r];
#pragma unroll
          for (int r = 0; r < 4; ++r) pw[((6 + mt) * 16 + lq * 4 + r) * 17 + lm] = gi[r];
        }
      }
      __syncthreads();
      {
        const int bb = tid >> 4, dl = tid & 15;
        const int mtb = bb >> 4, bl = bb & 15;
        float rg = sigm(pw[((mtb * 3 + 0) * 16 + bl) * 17 + dl]);
        float zg = sigm(pw[((mtb * 3 + 1) * 16 + bl) * 17 + dl]);
        float hn = pw[((mtb * 3 + 2) * 16 + bl) * 17 + dl];
        float inn = pw[((6 + mtb) * 16 + bl) * 17 + dl];
        float nn = tanhfast(fmaf(rg, hn, inn));
        const int d = dt * 16 + dl;
        float ho = btof(((unsigned short*)hA)[((bb >> 4) * 16 + (d >> 5)) * 512 +
                                              (((d >> 3) & 3) * 16 + (bb & 15)) * 8 +
                                              (d & 7)]);
        float hnew = fmaxf(0.0f, fmaf(zg, ho - nn, nn));
        h16[bb * 16 + dl] = f2bfbits(hnew);
      }
      __syncthreads();
      // fused single-wave publish: wave 0 reads h16 (16B/lane), one dwordx4
      // coherent store/lane, drain, lane 0 posts flag. No trailing sync.
      if (tid < 64) {
        u32x4 hv = *(const u32x4*)(h16 + 8 * tid);
        unsigned* dst = (unsigned*)(p.hbf + ((s + 1) & 3) * 16384) +
                        (tid >> 1) * 256 + dt * 8 + (tid & 1) * 4;
        sysst16_drain(dst, hv);
        if (tid == 0) sysst32(hdone + dt * 16, (unsigned)(s + 1));
      }
      // loop-top __syncthreads is the join
    }
  } else {
    // ============================ MEL path ============================
    const int mt = bid - 160;  // batch half
    const int wv = tid >> 6;
    const bool act = wv < 6;
    const int l = tid & 63, lm = l & 15, lq = l >> 4;
    const int nt = wv;
    const int bn = nt * 16 + lm;
    __hip_bfloat16* hA = (__hip_bfloat16*)smem;
    __hip_bfloat16* cA = (__hip_bfloat16*)(smem + 32768);  // 64KB, K=1024
    p0a_worker(p, (bid - 128) * 512 + tid);
    if (tid == 0) {
      while (sysld32(p.bar) != FLAGS_MAGIC) __builtin_amdgcn_s_sleep(1);
    }
    p0bar(p.bar);
    bf8 WMC[8], WMH[16];
    float bias = 0.f;
    if (act) {
#pragma unroll
      for (int kt = 0; kt < 8; ++kt) WMC[kt] = ldfrag(p.wmelgb + bn * 768 + kt * 32 + lq * 8);
#pragma unroll
      for (int kt = 0; kt < 16; ++kt)
        WMH[kt] = ldfrag(p.wmelgb + bn * 768 + 256 + kt * 32 + lq * 8);
      bias = (bn < 80) ? p.bmel[bn] : ((bn == 80) ? p.bgate[0] : 0.f);
    }
    for (int tau = 0; tau < 64; ++tau) {
      if (tid < 32) waitge(hdone + tid * 16, (unsigned)(tau + 1));
      else if (tid >= 64 && tid < 192) waitge(ctxdone + (tid - 64) * 16, (unsigned)(tau + 1));
      __syncthreads();
      stage_h_frag(hA, p.hbf + ((tau + 1) & 3) * 16384, tid);
      stage_c4(cA, p.ctxb + (tau & 3) * 32768, tid);
      __syncthreads();
      if (act) {
        f32x4 acc = {0.f, 0.f, 0.f, 0.f};
#pragma unroll
        for (int kt = 0; kt < 48; ++kt) {
          bf8 a = (kt < 32) ? ldfrag(cA + (mt * 32 + kt) * 512 + l * 8)
                            : ldfrag(hA + (mt * 16 + (kt - 32)) * 512 + l * 8);
          bf8 bb2 = (kt < 32) ? WMC[kt & 7] : WMH[kt - 32];
          acc = MFMA16(a, bb2, acc);
        }
#pragma unroll
        for (int r = 0; r < 4; ++r) {
          int bb = mt * 16 + lq * 4 + r;
          float v = acc[r] + bias;
          if (bn < 80)
            p.out[bb * 5120 + bn * 64 + tau] = v;
          else if (bn == 80)
            p.out[163840 + bb * 64 + tau] = v;
        }
      }
      __syncthreads();
      if (tid == 0) sysst32(meldone + mt * 16, (unsigned)(tau + 1));
    }
  }
}

extern "C" void kernel_launch(void* const* d_in, const int* in_sizes, int n_in,
                              void* d_out, int out_size, void* d_ws, size_t ws_size,
                              hipStream_t stream) {
  Params P;
  P.dec = (const float*)d_in[0];
  P.ali = (const float*)d_in[1];
  P.watt = (const float*)d_in[2];
  P.wih = (const float*)d_in[3];
  P.whh = (const float*)d_in[4];
  P.wmel = (const float*)d_in[5];
  P.bmel = (const float*)d_in[6];
  P.wgate = (const float*)d_in[7];
  P.bgate = (const float*)d_in[8];
  P.out = (float*)d_out;

  char* w = (char*)d_ws;
  size_t o = 0;
  auto nxt = [&](size_t b) {
    char* r = w + o;
    o += (b + 255) & ~(size_t)255;
    return r;
  };
  P.bar = (unsigned*)nxt(16384);
  P.wihb = (__hip_bfloat16*)nxt(1536 * 512 * 2);
  P.whhb = (__hip_bfloat16*)nxt(1536 * 512 * 2);
  P.wmelgb = (__hip_bfloat16*)nxt(96 * 768 * 2);
  P.seqb = (__hip_bfloat16*)nxt(64 * 32 * 256 * 2);
  P.hbf = (__hip_bfloat16*)nxt(4 * 32 * 512 * 2);
  P.ctxb = (__hip_bfloat16*)nxt(4 * 128 * 256 * 2);
  P.wattp = (unsigned*)nxt(256 * 256 * 4);

  (void)hipFuncSetAttribute((const void*)rdec_kernel,
                            hipFuncAttributeMaxDynamicSharedMemorySize, SMEM_BYTES);

  void* args[] = {&P};
  hipError_t err = hipLaunchCooperativeKernel((void*)rdec_kernel, dim3(NBLK), dim3(512),
                                              args, SMEM_BYTES, stream);
  if (err != hipSuccess) {
    rdec_kernel<<<dim3(NBLK), dim3(512), SMEM_BYTES, stream>>>(P);
  }
}

// Round 8
// 809.578 us; speedup vs baseline: 1.0950x; 1.0950x over previous
//
#include <hip/hip_runtime.h>
#include <hip/hip_bf16.h>

// ============================================================================
// RecurrentDecoder v17: 162-block persistent kernel, flag dataflow.
// v16 post-mortem: both overlap edits regressed (+1.15us/step pure stall;
// long-spinning 128-line system-scope polls congest the fabric the producers
// need). Reverted to v13 structure entirely.
// v13 -> v17: step-unique rings => plain cached consumer reads.
//  - hbf becomes [65][32][512] (slot s = h(s)), ctxb becomes [64][128][256]
//    (slot s = ctx(s)). No address reuse within the dispatch, so consumer
//    reads need NO sc0/sc1: first touch per XCD fetches the write-through
//    data from the coherence point, and co-XCD blocks share it in L2.
//    Producers unchanged: sc0sc1 dword stores + syncthreads drain + flag.
//    (Same visibility pattern as the P0-staged weights, which are already
//    plain-read every step after p0bar's agent fence.)
//  - Coherent fabric traffic per step drops ~4-16x on the h->att, h->GRU
//    and ctx->GRU legs (was 128 blocks x 1KB + 32 x 32KB + 32 x 64KB of
//    L2-bypassing reads per step against tiny hot regions).
//  - No slot reuse => meldone backpressure is unnecessary: all meldone
//    polls/posts deleted (one fewer poll leg in att and GRU loop tops).
// Everything else byte-identical to v13: 4-way e-split att (128 blocks),
// block-local softmax, shfl 8/16/32, partial-ctx quarters, GRU K=1024 with
// WC[kt&7], 2-wave publish + sync-drain + flag, s_sleep waitge, mel 160/161.
// ============================================================================

#define LOG2E 1.4426950408889634f
#define FLAGS_MAGIC 0x13572468u
#define SMEM_BYTES 138752
#define NBLK 162

typedef __attribute__((ext_vector_type(8))) short bf8;
typedef __attribute__((ext_vector_type(4))) float f32x4;
typedef __attribute__((ext_vector_type(4))) unsigned u32x4;
typedef unsigned long long ull;

#define EX2(x) exp2f(x)
#define MFMA16(a, b, c) __builtin_amdgcn_mfma_f32_16x16x32_bf16(a, b, c, 0, 0, 0)

struct Params {
  const float* dec;
  const float* ali;
  const float* watt;
  const float* wih;
  const float* whh;
  const float* wmel;
  const float* bmel;
  const float* wgate;
  const float* bgate;
  float* out;
  unsigned* bar;  // [0]=magic [16]=p0cnt [32+16i]=hdone(32) [544+16j]=ctxdone(128)
  __hip_bfloat16* wihb;    // [1536][512]
  __hip_bfloat16* whhb;    // [1536][512]
  __hip_bfloat16* wmelgb;  // [96][768]
  __hip_bfloat16* seqb;    // [64][32][256]
  __hip_bfloat16* hbf;     // [65][32][512]   slot s = h(s), step-unique
  __hip_bfloat16* ctxb;    // [64][128][256]  slot s = ctx(s) (hb = q4*32+b)
  unsigned* wattp;         // [256][256] packed bf16 pairs of W_att^T
};

__device__ __forceinline__ bf8 ldfrag(const __hip_bfloat16* p) { return *(const bf8*)p; }
__device__ __forceinline__ float sigm(float x) { return 1.0f / (1.0f + EX2(-x * LOG2E)); }
__device__ __forceinline__ float tanhfast(float x) {
  x = fminf(fmaxf(x, -15.0f), 15.0f);
  float e = EX2(x * (2.0f * LOG2E));
  return (e - 1.0f) / (e + 1.0f);
}
__device__ __forceinline__ float btof(unsigned v) { return __uint_as_float(v << 16); }
__device__ __forceinline__ unsigned short f2bfbits(float x) {
  __hip_bfloat16 h = __float2bfloat16(x);
  return *(unsigned short*)&h;
}
__device__ __forceinline__ unsigned sysld32(const unsigned* p) {
  return __hip_atomic_load(p, __ATOMIC_RELAXED, __HIP_MEMORY_SCOPE_SYSTEM);
}
__device__ __forceinline__ void sysst32(unsigned* p, unsigned v) {
  __hip_atomic_store(p, v, __ATOMIC_RELAXED, __HIP_MEMORY_SCOPE_SYSTEM);
}
__device__ __forceinline__ void waitge(unsigned* w, unsigned tgt) {
  while (sysld32(w) < tgt) __builtin_amdgcn_s_sleep(1);
}

__device__ __forceinline__ void p0bar(unsigned* bar) {
  __syncthreads();
  if (threadIdx.x == 0) {
    __builtin_amdgcn_fence(__ATOMIC_RELEASE, "agent");
    __hip_atomic_fetch_add(bar + 16, 1u, __ATOMIC_RELAXED, __HIP_MEMORY_SCOPE_SYSTEM);
    while (sysld32(bar + 16) < (unsigned)NBLK) __builtin_amdgcn_s_sleep(1);
    __builtin_amdgcn_fence(__ATOMIC_ACQUIRE, "agent");
  }
  __syncthreads();
}

// P0 conversion work for blocks 128..161 (wid in [0, 34*512))
__device__ __forceinline__ void p0a_worker(const Params& p, int wid) {
  for (int i = wid; i < 2252800; i += 17408) {
    if (i < 786432) {
      p.wihb[i] = __float2bfloat16(p.wih[i]);
    } else if (i < 1572864) {
      int j = i - 786432;
      p.whhb[j] = __float2bfloat16(p.whh[j]);
    } else if (i < 2097152) {
      int j = i - 1572864;
      int s = j >> 13;
      p.seqb[j] = (s == 0) ? __float2bfloat16(0.0f) : __float2bfloat16(p.dec[j - 8192]);
    } else if (i < 2170880) {
      int j = i - 2097152;
      int r = j / 768, c = j - r * 768;
      float v = (r < 80) ? p.wmel[j] : ((r == 80) ? p.wgate[c] : 0.0f);
      p.wmelgb[j] = __float2bfloat16(v);
    } else if (i < 2236416) {
      int j = i - 2170880;
      int kp = j >> 8, e = j & 255;
      unsigned lo = f2bfbits(p.watt[e * 512 + 2 * kp]);
      unsigned hi = f2bfbits(p.watt[e * 512 + 2 * kp + 1]);
      p.wattp[j] = lo | (hi << 16);
    } else {
      int j = i - 2236416;
      p.hbf[j] = __float2bfloat16(0.0f);  // hbf slot 0 = h(0) = 0
    }
  }
}

// Stage h[32][512] (row-major, PLAIN cached loads) into fragment-major LDS.
__device__ __forceinline__ void stage_h_frag(__hip_bfloat16* hA,
                                             const __hip_bfloat16* hsrc, int tid) {
  const int lm = tid & 15, lq = (tid >> 4) & 3, wq = tid >> 6;
  const int dst_in = (lq * 16 + lm) * 8;
  const int i0 = wq, i1 = 8 + wq, i2 = 16 + wq, i3 = 24 + wq;
  auto soff = [&](int idx) {
    return ((idx >> 4) * 16 + lm) * 512 + (idx & 15) * 32 + lq * 8;
  };
  u32x4 a = *(const u32x4*)(hsrc + soff(i0));
  u32x4 b = *(const u32x4*)(hsrc + soff(i1));
  u32x4 c = *(const u32x4*)(hsrc + soff(i2));
  u32x4 d = *(const u32x4*)(hsrc + soff(i3));
  u32x4* dst = (u32x4*)hA;
  dst[(i0 * 512 + dst_in) >> 3] = a;
  dst[(i1 * 512 + dst_in) >> 3] = b;
  dst[(i2 * 512 + dst_in) >> 3] = c;
  dst[(i3 * 512 + dst_in) >> 3] = d;
}
// Stage concat-ctx [b, k=q4*256+e] (src slot: [128][256], hb=q4*32+b) into
// fragment-major LDS (64 sections over K=1024). PLAIN cached loads.
__device__ __forceinline__ void stage_c4(__hip_bfloat16* cA,
                                         const __hip_bfloat16* csrc, int tid) {
  const int lm = tid & 15, lq = (tid >> 4) & 3, wq = tid >> 6;
  const int dst_in = (lq * 16 + lm) * 8;
  u32x4* dst = (u32x4*)cA;
  auto soff = [&](int idx) {
    int mt = idx >> 5, kt = idx & 31;
    int bb = mt * 16 + lm;
    int k = kt * 32 + lq * 8;
    return ((k >> 8) * 32 + bb) * 256 + (k & 255);
  };
#pragma unroll
  for (int r = 0; r < 8; ++r) {
    const int idx = r * 8 + wq;
    u32x4 v = *(const u32x4*)(csrc + soff(idx));
    dst[(idx * 512 + dst_in) >> 3] = v;
  }
}

__global__ void __launch_bounds__(512, 1) rdec_kernel(Params p) {
  const int tid = threadIdx.x;
  const int bid = blockIdx.x;
  extern __shared__ char smem[];
  unsigned* hdone = p.bar + 32;     // 32 flags
  unsigned* ctxdone = p.bar + 544;  // 128 flags

  if (bid == 0) {
    for (int i = 1 + tid; i < 2624; i += 512) sysst32(p.bar + i, 0u);
    __syncthreads();
    if (tid == 0) sysst32(p.bar, FLAGS_MAGIC);
  }

  if (bid < 128) {
    // =================== ATT path (batch b, e-quarter q4) ===================
    const int b = bid >> 2, q4 = bid & 3, hb = q4 * 32 + b;
    unsigned short* alds = (unsigned short*)smem;  // [256 f][260 t] bf16 (pad)
    float* fb = (float*)(smem + 133120);
    float* shh = fb;          // 512   h(s)[b,:]
    float* p2l = fb + 512;    // 64    proj_e * LOG2E (my e-quarter)
    float* rzl = fb + 576;    // 64    1/Z_e
    float* tw = fb + 640;     // 256   tw (my e-quarter contribution)
    float* cp = fb + 896;     // [2][256] ctx partial reduce

    // el in lane LOW bits (bank spread), kq in lane bits 3..5 (shfl 8/16/32)
    const int el = (tid & 7) | ((tid >> 6) << 3);  // e-local / t-quad (0..63)
    const int kq = (tid >> 3) & 7;                 // k-/t-eighth / e-group
    const int f = tid & 255, th = tid >> 8;        // ctx mapping

    // P0: full a[:,b,:] -> alds[f][t]
    for (int i = tid; i < 65536; i += 512) {
      int t = i >> 8, ee = i & 255;
      alds[ee * 260 + t] = f2bfbits(p.ali[t * 8192 + b * 256 + ee]);
    }
    if (tid == 0) {
      while (sysld32(p.bar) != FLAGS_MAGIC) __builtin_amdgcn_s_sleep(1);
    }
    p0bar(p.bar);
    // k-strided weight regs: kp = i*8 + kq
    unsigned wr[32];
#pragma unroll
    for (int i = 0; i < 32; ++i) wr[i] = p.wattp[(i * 8 + kq) * 256 + q4 * 64 + el];

    for (int s = 0; s < 64; ++s) {
      if (tid < 32) waitge(hdone + tid * 16, (unsigned)s);
      __syncthreads();
      // h(s)[b,:] -> shh fp32 (plain cached read of step-unique slot)
      if (tid < 128) {
        ull w = ((const ull*)(p.hbf + s * 16384 + b * 512))[tid];
        shh[tid * 4 + 0] = btof((unsigned)(w & 0xffff));
        shh[tid * 4 + 1] = btof((unsigned)((w >> 16) & 0xffff));
        shh[tid * 4 + 2] = btof((unsigned)((w >> 32) & 0xffff));
        shh[tid * 4 + 3] = btof((unsigned)((w >> 48) & 0xffff));
      }
      __syncthreads();
      // proj (k-eighth) + Z (t-eighth) fused in-register, shfl 8/16/32
      {
        const float2* h2 = (const float2*)shh;
        float a0 = 0.f, a1 = 0.f;
#pragma unroll
        for (int i = 0; i < 32; i += 2) {
          unsigned w0 = wr[i], w1 = wr[i + 1];
          float2 h0 = h2[i * 8 + kq], h1 = h2[(i + 1) * 8 + kq];
          a0 = fmaf(__uint_as_float(w0 << 16), h0.x, a0);
          a0 = fmaf(__uint_as_float(w0 & 0xffff0000u), h0.y, a0);
          a1 = fmaf(__uint_as_float(w1 << 16), h1.x, a1);
          a1 = fmaf(__uint_as_float(w1 & 0xffff0000u), h1.y, a1);
        }
        float pr = a0 + a1;
        pr += __shfl_xor(pr, 8);
        pr += __shfl_xor(pr, 16);
        pr += __shfl_xor(pr, 32);
        const float pp = pr * LOG2E;
        // Z partial over my t-eighth (32 t)
        const unsigned short* ap = alds + (q4 * 64 + el) * 260 + kq * 32;
        float z0 = 0.f, z1 = 0.f;
#pragma unroll
        for (int j = 0; j < 8; ++j) {
          ushort4 v = *(const ushort4*)(ap + j * 4);
          z0 += EX2(btof(v.x) * pp) + EX2(btof(v.y) * pp);
          z1 += EX2(btof(v.z) * pp) + EX2(btof(v.w) * pp);
        }
        float zz = z0 + z1;
        zz += __shfl_xor(zz, 8);
        zz += __shfl_xor(zz, 16);
        zz += __shfl_xor(zz, 32);
        if (kq == 0) {
          p2l[el] = pp;
          rzl[el] = 1.0f / zz;
        }
      }
      __syncthreads();
      // pass2: tw_t = sum_e u/Z over my 64 e; shfl 8/16/32 over e-groups
      {
        float t0 = 0.f, t1 = 0.f, t2 = 0.f, t3 = 0.f;
#pragma unroll
        for (int j = 0; j < 8; ++j) {
          const int e2 = kq * 8 + j;
          ushort4 v = *(const ushort4*)(alds + (q4 * 64 + e2) * 260 + el * 4);
          const float ppj = p2l[e2], rr = rzl[e2];
          t0 = fmaf(EX2(btof(v.x) * ppj), rr, t0);
          t1 = fmaf(EX2(btof(v.y) * ppj), rr, t1);
          t2 = fmaf(EX2(btof(v.z) * ppj), rr, t2);
          t3 = fmaf(EX2(btof(v.w) * ppj), rr, t3);
        }
        t0 += __shfl_xor(t0, 8); t0 += __shfl_xor(t0, 16); t0 += __shfl_xor(t0, 32);
        t1 += __shfl_xor(t1, 8); t1 += __shfl_xor(t1, 16); t1 += __shfl_xor(t1, 32);
        t2 += __shfl_xor(t2, 8); t2 += __shfl_xor(t2, 16); t2 += __shfl_xor(t2, 32);
        t3 += __shfl_xor(t3, 8); t3 += __shfl_xor(t3, 16); t3 += __shfl_xor(t3, 32);
        if (kq == 0) *(float4*)(tw + el * 4) = make_float4(t0, t1, t2, t3);
      }
      __syncthreads();
      // ctx partial: ALL 256 f, t-half per th (sum of 4 quarters lands in GRU MFMA)
      {
        const unsigned short* ap = alds + f * 260 + th * 128;
        const float4* twv = (const float4*)(tw + th * 128);
        float c0 = 0.f, c1 = 0.f;
#pragma unroll 4
        for (int j = 0; j < 32; ++j) {
          ushort4 v = *(const ushort4*)(ap + j * 4);
          float4 t4 = twv[j];
          c0 += t4.x * btof(v.x) + t4.y * btof(v.y);
          c1 += t4.z * btof(v.z) + t4.w * btof(v.w);
        }
        cp[th * 256 + f] = c0 + c1;
      }
      __syncthreads();
      // combine + pack + publish fused (128 threads, 2 f each; write-through)
      if (tid < 128) {
        float2 ca = ((const float2*)cp)[tid];
        float2 cb = ((const float2*)(cp + 256))[tid];
        float cv0 = ca.x + cb.x, cv1 = ca.y + cb.y;
        unsigned u = (unsigned)f2bfbits(cv0) | ((unsigned)f2bfbits(cv1) << 16);
        sysst32((unsigned*)(p.ctxb + (s * 128 + hb) * 256) + tid, u);
      }
      __syncthreads();
      if (tid == 0) sysst32(ctxdone + hb * 16, (unsigned)(s + 1));
    }
  } else if (bid < 160) {
    // ============================ GRU path ============================
    const int dt = bid - 128;
    const int wv = tid >> 6;
    const bool act = wv < 6;
    const int l = tid & 63, lm = l & 15, lq = l >> 4;
    const int g = wv % 3, mt = wv / 3;
    const int am = mt * 16 + lm;
    const int brow = g * 512 + dt * 16 + lm;
    __hip_bfloat16* hA = (__hip_bfloat16*)smem;             // frag-major 32KB
    __hip_bfloat16* cA = (__hip_bfloat16*)(smem + 32768);   // frag-major 64KB (K=1024)
    float* pw = (float*)(smem + 98304);                     // [8][16][17]
    unsigned short* h16 = (unsigned short*)(smem + 107008); // [512]
    p0a_worker(p, (bid - 128) * 512 + tid);
    if (tid == 0) {
      while (sysld32(p.bar) != FLAGS_MAGIC) __builtin_amdgcn_s_sleep(1);
    }
    p0bar(p.bar);
    bf8 WH[16], WD[8], WC[8];
    if (act) {
#pragma unroll
      for (int kt = 0; kt < 16; ++kt) WH[kt] = ldfrag(p.whhb + brow * 512 + kt * 32 + lq * 8);
#pragma unroll
      for (int kt = 0; kt < 8; ++kt) WD[kt] = ldfrag(p.wihb + brow * 512 + kt * 32 + lq * 8);
#pragma unroll
      for (int kt = 0; kt < 8; ++kt) WC[kt] = ldfrag(p.wihb + brow * 512 + 256 + kt * 32 + lq * 8);
    }
    for (int s = 0; s < 64; ++s) {
      if (tid < 32) waitge(hdone + tid * 16, (unsigned)s);
      __syncthreads();
      stage_h_frag(hA, p.hbf + s * 16384, tid);
      __syncthreads();
      f32x4 acc = {0.f, 0.f, 0.f, 0.f};
      f32x4 gi = {0.f, 0.f, 0.f, 0.f};
      if (act) {
#pragma unroll
        for (int kt = 0; kt < 16; ++kt) {
          bf8 a = ldfrag(hA + (mt * 16 + kt) * 512 + l * 8);
          acc = MFMA16(a, WH[kt], acc);
        }
        const __hip_bfloat16* seqp = p.seqb + s * 8192;
#pragma unroll
        for (int kt = 0; kt < 8; ++kt) {
          bf8 a = ldfrag(seqp + am * 256 + kt * 32 + lq * 8);
          gi = MFMA16(a, WD[kt], gi);
        }
      }
      if (tid < 128) waitge(ctxdone + tid * 16, (unsigned)(s + 1));
      __syncthreads();
      stage_c4(cA, p.ctxb + s * 32768, tid);
      __syncthreads();
      if (act) {
        // gi_ctx over K=1024 concat quarters with duplicated W rows
#pragma unroll
        for (int kt = 0; kt < 32; ++kt) {
          bf8 a = ldfrag(cA + (mt * 32 + kt) * 512 + l * 8);
          gi = MFMA16(a, WC[kt & 7], gi);
        }
        if (g < 2) {
#pragma unroll
          for (int r = 0; r < 4; ++r) pw[(wv * 16 + lq * 4 + r) * 17 + lm] = acc[r] + gi[r];
        } else {
#pragma unroll
          for (int r = 0; r < 4; ++r) pw[(wv * 16 + lq * 4 + r) * 17 + lm] = acc[r];
#pragma unroll
          for (int r = 0; r < 4; ++r) pw[((6 + mt) * 16 + lq * 4 + r) * 17 + lm] = gi[r];
        }
      }
      __syncthreads();
      {
        const int bb = tid >> 4, dl = tid & 15;
        const int mtb = bb >> 4, bl = bb & 15;
        float rg = sigm(pw[((mtb * 3 + 0) * 16 + bl) * 17 + dl]);
        float zg = sigm(pw[((mtb * 3 + 1) * 16 + bl) * 17 + dl]);
        float hn = pw[((mtb * 3 + 2) * 16 + bl) * 17 + dl];
        float inn = pw[((6 + mtb) * 16 + bl) * 17 + dl];
        float nn = tanhfast(fmaf(rg, hn, inn));
        const int d = dt * 16 + dl;
        float ho = btof(((unsigned short*)hA)[((bb >> 4) * 16 + (d >> 5)) * 512 +
                                              (((d >> 3) & 3) * 16 + (bb & 15)) * 8 +
                                              (d & 7)]);
        float hnew = fmaxf(0.0f, fmaf(zg, ho - nn, nn));
        h16[bb * 16 + dl] = f2bfbits(hnew);
      }
      __syncthreads();
      if (tid < 256) {
        const int bb2 = tid >> 3, dp = tid & 7;
        unsigned v = (unsigned)h16[bb2 * 16 + dp * 2] |
                     ((unsigned)h16[bb2 * 16 + dp * 2 + 1] << 16);
        sysst32((unsigned*)(p.hbf + (s + 1) * 16384) + bb2 * 256 + dt * 8 + dp, v);
      }
      __syncthreads();
      if (tid == 0) sysst32(hdone + dt * 16, (unsigned)(s + 1));
    }
  } else {
    // ============================ MEL path ============================
    const int mt = bid - 160;  // batch half
    const int wv = tid >> 6;
    const bool act = wv < 6;
    const int l = tid & 63, lm = l & 15, lq = l >> 4;
    const int nt = wv;
    const int bn = nt * 16 + lm;
    __hip_bfloat16* hA = (__hip_bfloat16*)smem;
    __hip_bfloat16* cA = (__hip_bfloat16*)(smem + 32768);  // 64KB, K=1024
    p0a_worker(p, (bid - 128) * 512 + tid);
    if (tid == 0) {
      while (sysld32(p.bar) != FLAGS_MAGIC) __builtin_amdgcn_s_sleep(1);
    }
    p0bar(p.bar);
    bf8 WMC[8], WMH[16];
    float bias = 0.f;
    if (act) {
#pragma unroll
      for (int kt = 0; kt < 8; ++kt) WMC[kt] = ldfrag(p.wmelgb + bn * 768 + kt * 32 + lq * 8);
#pragma unroll
      for (int kt = 0; kt < 16; ++kt)
        WMH[kt] = ldfrag(p.wmelgb + bn * 768 + 256 + kt * 32 + lq * 8);
      bias = (bn < 80) ? p.bmel[bn] : ((bn == 80) ? p.bgate[0] : 0.f);
    }
    for (int tau = 0; tau < 64; ++tau) {
      if (tid < 32) waitge(hdone + tid * 16, (unsigned)(tau + 1));
      else if (tid >= 64 && tid < 192) waitge(ctxdone + (tid - 64) * 16, (unsigned)(tau + 1));
      __syncthreads();
      stage_h_frag(hA, p.hbf + (tau + 1) * 16384, tid);
      stage_c4(cA, p.ctxb + tau * 32768, tid);
      __syncthreads();
      if (act) {
        f32x4 acc = {0.f, 0.f, 0.f, 0.f};
#pragma unroll
        for (int kt = 0; kt < 48; ++kt) {
          bf8 a = (kt < 32) ? ldfrag(cA + (mt * 32 + kt) * 512 + l * 8)
                            : ldfrag(hA + (mt * 16 + (kt - 32)) * 512 + l * 8);
          bf8 bb2 = (kt < 32) ? WMC[kt & 7] : WMH[kt - 32];
          acc = MFMA16(a, bb2, acc);
        }
#pragma unroll
        for (int r = 0; r < 4; ++r) {
          int bb = mt * 16 + lq * 4 + r;
          float v = acc[r] + bias;
          if (bn < 80)
            p.out[bb * 5120 + bn * 64 + tau] = v;
          else if (bn == 80)
            p.out[163840 + bb * 64 + tau] = v;
        }
      }
      __syncthreads();
    }
  }
}

extern "C" void kernel_launch(void* const* d_in, const int* in_sizes, int n_in,
                              void* d_out, int out_size, void* d_ws, size_t ws_size,
                              hipStream_t stream) {
  Params P;
  P.dec = (const float*)d_in[0];
  P.ali = (const float*)d_in[1];
  P.watt = (const float*)d_in[2];
  P.wih = (const float*)d_in[3];
  P.whh = (const float*)d_in[4];
  P.wmel = (const float*)d_in[5];
  P.bmel = (const float*)d_in[6];
  P.wgate = (const float*)d_in[7];
  P.bgate = (const float*)d_in[8];
  P.out = (float*)d_out;

  char* w = (char*)d_ws;
  size_t o = 0;
  auto nxt = [&](size_t b) {
    char* r = w + o;
    o += (b + 255) & ~(size_t)255;
    return r;
  };
  P.bar = (unsigned*)nxt(16384);
  P.wihb = (__hip_bfloat16*)nxt(1536 * 512 * 2);
  P.whhb = (__hip_bfloat16*)nxt(1536 * 512 * 2);
  P.wmelgb = (__hip_bfloat16*)nxt(96 * 768 * 2);
  P.seqb = (__hip_bfloat16*)nxt(64 * 32 * 256 * 2);
  P.hbf = (__hip_bfloat16*)nxt(65 * 32 * 512 * 2);    // step-unique h ring
  P.ctxb = (__hip_bfloat16*)nxt(64 * 128 * 256 * 2);  // step-unique ctx ring
  P.wattp = (unsigned*)nxt(256 * 256 * 4);

  (void)hipFuncSetAttribute((const void*)rdec_kernel,
                            hipFuncAttributeMaxDynamicSharedMemorySize, SMEM_BYTES);

  void* args[] = {&P};
  hipError_t err = hipLaunchCooperativeKernel((void*)rdec_kernel, dim3(NBLK), dim3(512),
                                              args, SMEM_BYTES, stream);
  if (err != hipSuccess) {
    rdec_kernel<<<dim3(NBLK), dim3(512), SMEM_BYTES, stream>>>(P);
  }
}